// Round 2
// baseline (397.568 us; speedup 1.0000x reference)
//
#include <hip/hip_runtime.h>
#include <hip/hip_bf16.h>

#define DIM   1024
#define NVEC  128
#define BROWS 32768

typedef short s16x8 __attribute__((ext_vector_type(8)));
typedef float f32x4 __attribute__((ext_vector_type(4)));

__device__ __forceinline__ unsigned short f2bf(float f) {
    union { float f; unsigned int u; } c; c.f = f;
    unsigned int u = c.u;
    u += 0x7fffu + ((u >> 16) & 1u);   // round-to-nearest-even
    return (unsigned short)(u >> 16);
}

// ---------------------------------------------------------------------------
// K1: per-column normalize v AND raw Gram row (rescale trick):
//   G[i][j] = <v_i_raw, v_j_raw> * rn_i * rn_j  (scaling applied in k_tinv)
// Block i: cache column i in LDS, reduce ss, write VnT/VnT16, then dot the
// cached column against coalesced rows of v for all j.
// ---------------------------------------------------------------------------
__global__ __launch_bounds__(256) void k_normgram(const float* __restrict__ v,
                                                  float* __restrict__ VnT,
                                                  unsigned short* __restrict__ VnT16,
                                                  float* __restrict__ rn_out,
                                                  float* __restrict__ G0) {
    int i = blockIdx.x, t = threadIdx.x;
    __shared__ float col[DIM];
    __shared__ float red[4];
    __shared__ float part[256];
    float c4[4]; float ss = 0.f;
#pragma unroll
    for (int u = 0; u < 4; ++u) {
        int d = t + u * 256;
        float val = v[d * NVEC + i];
        c4[u] = val; col[d] = val; ss += val * val;
    }
#pragma unroll
    for (int o = 32; o > 0; o >>= 1) ss += __shfl_down(ss, o, 64);
    if ((t & 63) == 0) red[t >> 6] = ss;
    __syncthreads();
    float rn = rsqrtf(red[0] + red[1] + red[2] + red[3]);
    if (t == 0) rn_out[i] = rn;
#pragma unroll
    for (int u = 0; u < 4; ++u) {
        int d = t + u * 256;
        float val = c4[u] * rn;
        VnT[i * DIM + d]   = val;
        VnT16[i * DIM + d] = f2bf(val);
    }
    // raw Gram row: thread t -> j = t&127, d-half = t>>7
    int j = t & 127, half = t >> 7;
    const float* vp = v + (size_t)(half * 512) * NVEC + j;
    float s = 0.f;
#pragma unroll 4
    for (int d = 0; d < 512; ++d)
        s += col[half * 512 + d] * vp[(size_t)d * NVEC];
    part[t] = s;                       // t == half*128 + j
    __syncthreads();
    if (t < 128) G0[i * NVEC + t] = part[t] + part[t + 128];
}

// ---------------------------------------------------------------------------
// K2: T = R^{-1}, R = 0.5*I + strict_upper(G), G = G0 * rn_i * rn_j
// (same blocked triangular inversion as before; rescale folded into load)
// ---------------------------------------------------------------------------
__global__ __launch_bounds__(256) void k_tinv(const float* __restrict__ G0,
                                              const float* __restrict__ rn,
                                              float* __restrict__ Tout) {
    __shared__ __align__(16) float Ts[NVEC * NVEC];   // 65536 B
    __shared__ float rs[NVEC];
    int t = threadIdx.x;
    if (t < NVEC) rs[t] = rn[t];
    __syncthreads();

    // phase 0: R into LDS (0.5 on diag, zeros below), with rn rescale
    {
        int i = t >> 1, jb = (t & 1) * 64;
        float rni = rs[i];
        for (int j = jb; j < jb + 64; j++) {
            float val = 0.f;
            if (j > i)       val = G0[i * NVEC + j] * rni * rs[j];
            else if (j == i) val = 0.5f;
            Ts[i * NVEC + j] = val;
        }
    }
    __syncthreads();

    // phase 1: invert 8 diagonal 16x16 blocks
    {
        int blk = t >> 4, c = t & 15, rb = blk * 16;
        float xs[16];
        if (t < 128) {
#pragma unroll
            for (int jj = 0; jj < 16; jj++) xs[jj] = (jj == c) ? 2.f : 0.f;
#pragma unroll
            for (int i = 14; i >= 0; i--) {
                float s = 0.f;
#pragma unroll
                for (int j = i + 1; j < 16; j++)
                    s += Ts[(rb + i) * NVEC + rb + j] * xs[j];
                if (i < c) xs[i] = -2.f * s;
            }
        }
        __syncthreads();
        if (t < 128) {
#pragma unroll
            for (int i = 0; i < 16; i++)
                if (i <= c) Ts[(rb + i) * NVEC + rb + c] = xs[i];
        }
        __syncthreads();
    }

    // phase 2: combine levels
#pragma unroll
    for (int L = 16; L <= 64; L <<= 1) {
        int tpp = L << 2;
        int p   = t / tpp;
        int rem = t % tpp;
        int r   = rem / (L >> 2);
        int c0  = (rem % (L >> 2)) << 2;
        int a0  = p * (L << 1), b0 = a0 + L;
        int npanel = L >> 4;
        for (int pi = 0; pi < npanel; pi++) {
            int gr = a0 + pi * 16 + r;
            f32x4 acc = {0.f, 0.f, 0.f, 0.f};
            for (int k = pi * 16 + r; k < L; k++)
                acc += Ts[gr * NVEC + a0 + k] *
                       *(const f32x4*)&Ts[(a0 + k) * NVEC + b0 + c0];
            *(f32x4*)&Ts[(64 + r) * NVEC + p * L + c0] = acc;
            __syncthreads();
            f32x4 acc2 = {0.f, 0.f, 0.f, 0.f};
            for (int k = 0; k <= c0 + 3; k++)
                acc2 += Ts[(64 + r) * NVEC + p * L + k] *
                        *(const f32x4*)&Ts[(b0 + k) * NVEC + b0 + c0];
            *(f32x4*)&Ts[gr * NVEC + b0 + c0] = -acc2;
            __syncthreads();
        }
    }

    for (int idx = t; idx < NVEC * NVEC; idx += 256) {
        int i = idx >> 7, j = idx & 127;
        Tout[idx] = (j >= i) ? Ts[idx] : 0.f;
    }
}

// ---------------------------------------------------------------------------
// K3: W[d][i] = sum_j Vn[d][j] * T[i][j]  (T has explicit zeros below diag)
// Block = 8 d-values; T staged in LDS (pad 130 -> <=2-way banks); Vn reads
// 32B-coalesced. 128 blocks x 256 threads (thread = dl 0..7 x ig 0..31).
// ---------------------------------------------------------------------------
__global__ __launch_bounds__(256) void k_wmat(const float* __restrict__ VnT,
                                              const float* __restrict__ T,
                                              unsigned short* __restrict__ W16) {
    __shared__ float Tl[NVEC * 130];
    int t = threadIdx.x;
#pragma unroll
    for (int m = 0; m < 32; ++m) {
        int idx = t * 2 + m * 512;
        float2 f = *(const float2*)(T + idx);
        int r = idx >> 7, c = idx & 127;
        *(float2*)&Tl[r * 130 + c] = f;
    }
    __syncthreads();
    int dl = t & 7, ig = t >> 3;
    int d  = blockIdx.x * 8 + dl;
    int i0 = ig * 4;
    float a0 = 0.f, a1 = 0.f, a2 = 0.f, a3 = 0.f;
#pragma unroll 4
    for (int j = 0; j < NVEC; ++j) {
        float vn = VnT[(size_t)j * DIM + d];
        a0 += vn * Tl[(i0 + 0) * 130 + j];
        a1 += vn * Tl[(i0 + 1) * 130 + j];
        a2 += vn * Tl[(i0 + 2) * 130 + j];
        a3 += vn * Tl[(i0 + 3) * 130 + j];
    }
    ushort4 h; h.x = f2bf(a0); h.y = f2bf(a1); h.z = f2bf(a2); h.w = f2bf(a3);
    *(ushort4*)(W16 + (size_t)d * NVEC + i0) = h;
}

// ---------------------------------------------------------------------------
// K4 (fused, pipelined): per 64-row block:
//   phase A: Y = x @ Vn (K=1024), double-buffered staging, 1 barrier/step,
//            loads for step t+1 issued BEFORE MFMA of step t.
//   phase B: out = x - Y @ W^T + b, 8 column tiles, double-buffered W.
// All LDS tiles XOR-swizzled (no pad): rows 128B use ^(row&7)<<4,
// rows 256B use ^(row&15)<<4 -> <=2-way bank access on ds_read_b128.
// LDS: max(phaseA 48KB dbuf, Ys 16KB + Ws dbuf 64KB) = 80KB -> 2 blocks/CU.
// ---------------------------------------------------------------------------
__global__ __launch_bounds__(256) void k_fused(const float* __restrict__ x,
                                               const unsigned short* __restrict__ VnT16,
                                               const unsigned short* __restrict__ W16,
                                               const float* __restrict__ bias,
                                               float* __restrict__ out) {
    __shared__ __align__(16) unsigned short smem[40960];   // 81920 B
    unsigned short* As0 = smem;              // [64][64]   8 KB
    unsigned short* Bs0 = smem + 4096;       // [128][64] 16 KB
    unsigned short* As1 = smem + 12288;
    unsigned short* Bs1 = smem + 16384;      // phase A total 48 KB
    unsigned short* Ys  = smem;              // [64][128] 16 KB
    unsigned short* Ws0 = smem + 8192;       // [128][128] 32 KB
    unsigned short* Ws1 = smem + 24576;      // total 80 KB

    int t = threadIdx.x;
    int r0 = blockIdx.x * 64;
    int w = t >> 6, l = t & 63, q = l >> 4, lm = l & 15;

    int sArow = t >> 2, sAseg = t & 3;       // x-tile staging map
    int sBrow = t >> 1, sBhalf = t & 1;      // Vn/W staging map

    float4 xf[4]; uint4 bvr[4];

    auto ldA = [&](int k0) {
        const float4* src = (const float4*)(x + (size_t)(r0 + sArow) * DIM + k0);
#pragma unroll
        for (int jj = 0; jj < 4; jj++) xf[jj] = src[sAseg + jj * 4];
        const uint4* bsrc = (const uint4*)(VnT16 + (size_t)sBrow * DIM + k0 + sBhalf * 32);
#pragma unroll
        for (int jj = 0; jj < 4; jj++) bvr[jj] = bsrc[jj];
    };
    auto stA = [&](unsigned short* A, unsigned short* B) {
        int aslot = (sArow & 7) << 4;
#pragma unroll
        for (int jj = 0; jj < 4; jj++) {
            ushort4 h;
            h.x = f2bf(xf[jj].x); h.y = f2bf(xf[jj].y);
            h.z = f2bf(xf[jj].z); h.w = f2bf(xf[jj].w);
            *(ushort4*)((char*)A + sArow * 128 + ((sAseg * 8 + jj * 32) ^ aslot)) = h;
        }
        int bslot = (sBrow & 7) << 4;
#pragma unroll
        for (int jj = 0; jj < 4; jj++)
            *(uint4*)((char*)B + sBrow * 128 + ((sBhalf * 64 + jj * 16) ^ bslot)) = bvr[jj];
    };

    f32x4 acc[8];
#pragma unroll
    for (int n = 0; n < 8; n++) acc[n] = (f32x4){0.f, 0.f, 0.f, 0.f};

    int mslotA = (lm & 7) << 4;       // row&7 == lm&7 for all A/B frag rows
    int arow = w * 16 + lm;
    auto mmaA = [&](const unsigned short* A, const unsigned short* B) {
#pragma unroll
        for (int kk = 0; kk < 64; kk += 32) {
            s16x8 a = *(const s16x8*)((const char*)A + arow * 128 + (((kk + q * 8) * 2) ^ mslotA));
#pragma unroll
            for (int nt = 0; nt < 8; nt++) {
                int br = nt * 16 + lm;
                s16x8 b = *(const s16x8*)((const char*)B + br * 128 + (((kk + q * 8) * 2) ^ mslotA));
                acc[nt] = __builtin_amdgcn_mfma_f32_16x16x32_bf16(a, b, acc[nt], 0, 0, 0);
            }
        }
    };

    // ---------------- phase A ----------------
    ldA(0);
    stA(As0, Bs0);
    for (int tt = 0; tt < 16; tt += 2) {
        __syncthreads();
        ldA((tt + 1) * 64);           // issue next-tile loads (in flight over MFMA)
        mmaA(As0, Bs0);
        stA(As1, Bs1);                // vmcnt-wait lands here, after MFMA
        __syncthreads();
        if (tt + 2 < 16) ldA((tt + 2) * 64);
        mmaA(As1, Bs1);
        if (tt + 2 < 16) stA(As0, Bs0);
    }

    __syncthreads();                  // all phase-A LDS reads done before overwrite

    // Y (bf16) -> LDS, swizzled. C/D layout: col=lane&15, row=q*4+reg.
    {
        int yrow0 = w * 16 + q * 4;
#pragma unroll
        for (int nt = 0; nt < 8; nt++) {
#pragma unroll
            for (int r = 0; r < 4; r++) {
                int row = yrow0 + r;
                *(unsigned short*)((char*)Ys + row * 256 + ((nt * 32 + lm * 2) ^ ((row & 15) << 4)))
                    = f2bf(acc[nt][r]);
            }
        }
    }

    // ---------------- phase B ----------------
    uint4 wv[8];
    auto ldW = [&](int ct) {
        const uint4* src = (const uint4*)(W16 + (size_t)(ct * 128 + sBrow) * NVEC + sBhalf * 64);
#pragma unroll
        for (int jj = 0; jj < 8; jj++) wv[jj] = src[jj];
    };
    auto stW = [&](unsigned short* W) {
        int slot = (sBrow & 15) << 4;
#pragma unroll
        for (int jj = 0; jj < 8; jj++)
            *(uint4*)((char*)W + sBrow * 256 + ((sBhalf * 128 + jj * 16) ^ slot)) = wv[jj];
    };

    int mslotB = lm << 4;             // row&15 == lm for Ys and Ws frag rows
    auto mmaB_epi = [&](const unsigned short* W, int ct) {
        f32x4 oacc[8];
#pragma unroll
        for (int n = 0; n < 8; n++) oacc[n] = (f32x4){0.f, 0.f, 0.f, 0.f};
#pragma unroll
        for (int kk = 0; kk < 128; kk += 32) {
            s16x8 a = *(const s16x8*)((const char*)Ys + arow * 256 + (((kk + q * 8) * 2) ^ mslotB));
#pragma unroll
            for (int nt = 0; nt < 8; nt++) {
                int br = nt * 16 + lm;
                s16x8 b = *(const s16x8*)((const char*)W + br * 256 + (((kk + q * 8) * 2) ^ mslotB));
                oacc[nt] = __builtin_amdgcn_mfma_f32_16x16x32_bf16(a, b, oacc[nt], 0, 0, 0);
            }
        }
        int orow = r0 + w * 16 + q * 4;
#pragma unroll
        for (int nt = 0; nt < 8; nt++) {
            int col = ct * 128 + nt * 16 + lm;
            float bv = bias[col];
#pragma unroll
            for (int r = 0; r < 4; r++) {
                size_t idx = (size_t)(orow + r) * DIM + col;
                out[idx] = x[idx] - oacc[nt][r] + bv;   // x re-read is L3-resident
            }
        }
    };

    ldW(0);
    stW(Ws0);
    for (int ct = 0; ct < 8; ct += 2) {
        __syncthreads();
        ldW(ct + 1);
        mmaB_epi(Ws0, ct);
        stW(Ws1);
        __syncthreads();
        if (ct + 2 < 8) ldW(ct + 2);
        mmaB_epi(Ws1, ct + 1);
        if (ct + 2 < 8) stW(Ws0);
    }
}

// ---------------------------------------------------------------------------
extern "C" void kernel_launch(void* const* d_in, const int* in_sizes, int n_in,
                              void* d_out, int out_size, void* d_ws, size_t ws_size,
                              hipStream_t stream) {
    const float* x    = (const float*)d_in[0];
    const float* v    = (const float*)d_in[1];
    const float* bias = (const float*)d_in[2];
    float* out = (float*)d_out;

    char* ws = (char*)d_ws;
    float*          VnT   = (float*)(ws);                    // 512 KB  [NVEC][DIM] fp32
    unsigned short* VnT16 = (unsigned short*)(ws + 524288);  // 256 KB  [NVEC][DIM] bf16
    float*          G0    = (float*)(ws + 786432);           // 64 KB   raw Gram
    float*          T     = (float*)(ws + 851968);           // 64 KB
    float*          rn    = (float*)(ws + 917504);           // 512 B   col inv-norms
    unsigned short* W16   = (unsigned short*)(ws + 921600);  // 256 KB  [DIM][NVEC] bf16

    k_normgram<<<NVEC, 256, 0, stream>>>(v, VnT, VnT16, rn, G0);
    k_tinv<<<1, 256, 0, stream>>>(G0, rn, T);
    k_wmat<<<DIM / 8, 256, 0, stream>>>(VnT, T, W16);
    k_fused<<<BROWS / 64, 256, 0, stream>>>(x, VnT16, W16, bias, out);
}

// Round 3
// 335.027 us; speedup vs baseline: 1.1867x; 1.1867x over previous
//
#include <hip/hip_runtime.h>
#include <hip/hip_bf16.h>

#define DIM   1024
#define NVEC  128
#define BROWS 32768

typedef short s16x8 __attribute__((ext_vector_type(8)));
typedef float f32x4 __attribute__((ext_vector_type(4)));

__device__ __forceinline__ unsigned short f2bf(float f) {
    union { float f; unsigned int u; } c; c.f = f;
    unsigned int u = c.u;
    u += 0x7fffu + ((u >> 16) & 1u);   // round-to-nearest-even
    return (unsigned short)(u >> 16);
}

// async global->LDS, 16B per lane; LDS dest = wave-uniform base + lane*16
__device__ __forceinline__ void cp16(const void* g, void* l) {
    __builtin_amdgcn_global_load_lds(
        (const __attribute__((address_space(1))) unsigned int*)g,
        (__attribute__((address_space(3))) unsigned int*)l, 16, 0, 0);
}

// ---------------------------------------------------------------------------
// K1: per-column normalize v AND raw Gram row (rescale trick):
//   G[i][j] = <v_i_raw, v_j_raw> * rn_i * rn_j  (scaling applied in k_tinv)
// ---------------------------------------------------------------------------
__global__ __launch_bounds__(256) void k_normgram(const float* __restrict__ v,
                                                  float* __restrict__ VnT,
                                                  unsigned short* __restrict__ VnT16,
                                                  float* __restrict__ rn_out,
                                                  float* __restrict__ G0) {
    int i = blockIdx.x, t = threadIdx.x;
    __shared__ float col[DIM];
    __shared__ float red[4];
    __shared__ float part[256];
    float c4[4]; float ss = 0.f;
#pragma unroll
    for (int u = 0; u < 4; ++u) {
        int d = t + u * 256;
        float val = v[d * NVEC + i];
        c4[u] = val; col[d] = val; ss += val * val;
    }
#pragma unroll
    for (int o = 32; o > 0; o >>= 1) ss += __shfl_down(ss, o, 64);
    if ((t & 63) == 0) red[t >> 6] = ss;
    __syncthreads();
    float rn = rsqrtf(red[0] + red[1] + red[2] + red[3]);
    if (t == 0) rn_out[i] = rn;
#pragma unroll
    for (int u = 0; u < 4; ++u) {
        int d = t + u * 256;
        float val = c4[u] * rn;
        VnT[i * DIM + d]   = val;
        VnT16[i * DIM + d] = f2bf(val);
    }
    // raw Gram row: thread t -> j = t&127, d-half = t>>7
    int j = t & 127, half = t >> 7;
    const float* vp = v + (size_t)(half * 512) * NVEC + j;
    float s = 0.f;
#pragma unroll 4
    for (int d = 0; d < 512; ++d)
        s += col[half * 512 + d] * vp[(size_t)d * NVEC];
    part[t] = s;
    __syncthreads();
    if (t < 128) G0[i * NVEC + t] = part[t] + part[t + 128];
}

// ---------------------------------------------------------------------------
// K2: T = R^{-1}, R = 0.5*I + strict_upper(G), G = G0 * rn_i * rn_j
// ---------------------------------------------------------------------------
__global__ __launch_bounds__(256) void k_tinv(const float* __restrict__ G0,
                                              const float* __restrict__ rn,
                                              float* __restrict__ Tout) {
    __shared__ __align__(16) float Ts[NVEC * NVEC];   // 65536 B
    __shared__ float rs[NVEC];
    int t = threadIdx.x;
    if (t < NVEC) rs[t] = rn[t];
    __syncthreads();

    {   // phase 0: R into LDS (0.5 on diag, zeros below), rn rescale folded
        int i = t >> 1, jb = (t & 1) * 64;
        float rni = rs[i];
        for (int j = jb; j < jb + 64; j++) {
            float val = 0.f;
            if (j > i)       val = G0[i * NVEC + j] * rni * rs[j];
            else if (j == i) val = 0.5f;
            Ts[i * NVEC + j] = val;
        }
    }
    __syncthreads();

    {   // phase 1: invert 8 diagonal 16x16 blocks
        int blk = t >> 4, c = t & 15, rb = blk * 16;
        float xs[16];
        if (t < 128) {
#pragma unroll
            for (int jj = 0; jj < 16; jj++) xs[jj] = (jj == c) ? 2.f : 0.f;
#pragma unroll
            for (int i = 14; i >= 0; i--) {
                float s = 0.f;
#pragma unroll
                for (int j = i + 1; j < 16; j++)
                    s += Ts[(rb + i) * NVEC + rb + j] * xs[j];
                if (i < c) xs[i] = -2.f * s;
            }
        }
        __syncthreads();
        if (t < 128) {
#pragma unroll
            for (int i = 0; i < 16; i++)
                if (i <= c) Ts[(rb + i) * NVEC + rb + c] = xs[i];
        }
        __syncthreads();
    }

    // phase 2: combine levels
#pragma unroll
    for (int L = 16; L <= 64; L <<= 1) {
        int tpp = L << 2;
        int p   = t / tpp;
        int rem = t % tpp;
        int r   = rem / (L >> 2);
        int c0  = (rem % (L >> 2)) << 2;
        int a0  = p * (L << 1), b0 = a0 + L;
        int npanel = L >> 4;
        for (int pi = 0; pi < npanel; pi++) {
            int gr = a0 + pi * 16 + r;
            f32x4 acc = {0.f, 0.f, 0.f, 0.f};
            for (int k = pi * 16 + r; k < L; k++)
                acc += Ts[gr * NVEC + a0 + k] *
                       *(const f32x4*)&Ts[(a0 + k) * NVEC + b0 + c0];
            *(f32x4*)&Ts[(64 + r) * NVEC + p * L + c0] = acc;
            __syncthreads();
            f32x4 acc2 = {0.f, 0.f, 0.f, 0.f};
            for (int k = 0; k <= c0 + 3; k++)
                acc2 += Ts[(64 + r) * NVEC + p * L + k] *
                        *(const f32x4*)&Ts[(b0 + k) * NVEC + b0 + c0];
            *(f32x4*)&Ts[gr * NVEC + b0 + c0] = -acc2;
            __syncthreads();
        }
    }

    for (int idx = t; idx < NVEC * NVEC; idx += 256) {
        int i = idx >> 7, j = idx & 127;
        Tout[idx] = (j >= i) ? Ts[idx] : 0.f;
    }
}

// ---------------------------------------------------------------------------
// K3: W[d][i] = sum_j Vn[d][j] * T[i][j]   (T has explicit zeros below diag)
// ---------------------------------------------------------------------------
__global__ __launch_bounds__(256) void k_wmat(const float* __restrict__ VnT,
                                              const float* __restrict__ T,
                                              unsigned short* __restrict__ W16) {
    __shared__ float Tl[NVEC * 130];
    int t = threadIdx.x;
#pragma unroll
    for (int m = 0; m < 32; ++m) {
        int idx = t * 2 + m * 512;
        float2 f = *(const float2*)(T + idx);
        int r = idx >> 7, c = idx & 127;
        *(float2*)&Tl[r * 130 + c] = f;
    }
    __syncthreads();
    int dl = t & 7, ig = t >> 3;
    int d  = blockIdx.x * 8 + dl;
    int i0 = ig * 4;
    float a0 = 0.f, a1 = 0.f, a2 = 0.f, a3 = 0.f;
#pragma unroll 4
    for (int j = 0; j < NVEC; ++j) {
        float vn = VnT[(size_t)j * DIM + d];
        a0 += vn * Tl[(i0 + 0) * 130 + j];
        a1 += vn * Tl[(i0 + 1) * 130 + j];
        a2 += vn * Tl[(i0 + 2) * 130 + j];
        a3 += vn * Tl[(i0 + 3) * 130 + j];
    }
    ushort4 h; h.x = f2bf(a0); h.y = f2bf(a1); h.z = f2bf(a2); h.w = f2bf(a3);
    *(ushort4*)(W16 + (size_t)d * NVEC + i0) = h;
}

// ---------------------------------------------------------------------------
// K4 (fused): 512 blocks x 512 threads (8 waves, wave tile 16x64).
//   phase A: Y = x @ Vn (K=1024, BK=128): x reg-staged (fp32->bf16, swizzled
//            ds_write); Vn tile via global_load_lds w/ pre-swizzled source.
//            x loads for step s+1 issued before step-s MFMA (latency hidden).
//   phase B: out = x - Y @ W^T + b, 8 col-tiles; W via global_load_lds.
// LDS element (row,e) at byte (e*2) ^ ((row&15)<<4) within 256B rows (no pad)
//   -> ds_read_b128 fragments near-conflict-free (round-2 measured 1.5M cyc).
// gload_lds: LDS slot (row,chunk) holds logical chunk (chunk ^ (row&15)) --
//   source permutation == read permutation (involution), linear LDS dest.
// LDS exactly 48KB, aliased between phases. No lambdas (round-2 lesson:
//   captured arrays went to scratch -> +164MB WRITE_SIZE).
// ---------------------------------------------------------------------------
__global__ __launch_bounds__(512) void k_fused(const float* __restrict__ x,
                                               const unsigned short* __restrict__ VnT16,
                                               const unsigned short* __restrict__ W16,
                                               const float* __restrict__ bias,
                                               float* __restrict__ out) {
    __shared__ __align__(16) char smem[49152];           // 48 KB
    char* Asb = smem;                                    // [64][256B]  16KB (phase A)
    char* Bsb = smem + 16384;                            // [128][256B] 32KB (phase A)
    char* Ysb = smem;                                    // [64][256B]  16KB (phase B)
    char* Wsb = smem + 16384;                            // [128][256B] 32KB (phase B)

    const int t  = threadIdx.x;
    const int r0 = blockIdx.x * 64;
    const int w  = t >> 6, l = t & 63, q = l >> 4, lm = l & 15;
    const int wm = w & 3, wn = w >> 2;                   // wave tile: rows wm*16, cols wn*64
    const int lr = l >> 4, lc = l & 15;                  // gload lane -> (row, 16B-chunk)

    const int srow = t >> 3, sseg = t & 7;               // x staging: 64 rows x 8 segs
    const float* xrow = x + (size_t)(r0 + srow) * DIM;
    const int sw   = (srow & 15) << 4;
    const int arow = (wm * 16 + lm) * 256;
    const int ms   = lm << 4;

    float4 xf[4];

#define LDX(K0) { const float4* s4_ = (const float4*)(xrow + (K0));             \
        xf[0] = s4_[sseg]; xf[1] = s4_[sseg + 8];                               \
        xf[2] = s4_[sseg + 16]; xf[3] = s4_[sseg + 24]; }

#define STX() { _Pragma("unroll") for (int jj = 0; jj < 4; ++jj) {              \
        ushort4 h_; h_.x = f2bf(xf[jj].x); h_.y = f2bf(xf[jj].y);               \
        h_.z = f2bf(xf[jj].z); h_.w = f2bf(xf[jj].w);                           \
        *(ushort4*)(Asb + srow * 256 + ((sseg * 8 + jj * 64) ^ sw)) = h_; } }

#define GLB(K0) { _Pragma("unroll") for (int j_ = 0; j_ < 4; ++j_) {            \
        int row_ = w * 16 + j_ * 4 + lr;                                        \
        cp16(VnT16 + (size_t)row_ * DIM + (K0) + ((lc ^ (row_ & 15)) << 3),     \
             Bsb + (w * 16 + j_ * 4) * 256); } }

#define GLW(CT) { _Pragma("unroll") for (int j_ = 0; j_ < 4; ++j_) {            \
        int row_ = w * 16 + j_ * 4 + lr;                                        \
        cp16(W16 + (size_t)((CT) * 128 + row_) * NVEC + ((lc ^ (row_ & 15)) << 3), \
             Wsb + (w * 16 + j_ * 4) * 256); } }

    // ---------------- phase A: Y = x @ Vn ----------------
    f32x4 acc[4];
#pragma unroll
    for (int n = 0; n < 4; ++n) acc[n] = (f32x4){0.f, 0.f, 0.f, 0.f};

    LDX(0);
#pragma unroll 1
    for (int s = 0; s < 8; ++s) {
        __syncthreads();                 // prev MFMA done reading As/Bs
        STX();                           // waits xf vmcnt, swizzled ds_write
        GLB(s * 128);                    // async Vn tile -> LDS
        __syncthreads();                 // vmcnt(0)+lgkm drain: tiles ready
        if (s < 7) LDX((s + 1) * 128);   // next x tile in flight during MFMA
#pragma unroll
        for (int kk = 0; kk < 128; kk += 32) {
            s16x8 a = *(const s16x8*)(Asb + arow + (((kk + q * 8) * 2) ^ ms));
#pragma unroll
            for (int nt = 0; nt < 4; ++nt) {
                s16x8 b = *(const s16x8*)(Bsb + (wn * 64 + nt * 16 + lm) * 256
                                              + (((kk + q * 8) * 2) ^ ms));
                acc[nt] = __builtin_amdgcn_mfma_f32_16x16x32_bf16(a, b, acc[nt], 0, 0, 0);
            }
        }
    }

    __syncthreads();                     // all phase-A LDS reads done

    // Y (bf16) -> LDS, swizzled. C/D layout: col=lane&15, row=q*4+reg.
    {
        int yr0 = wm * 16 + q * 4;
#pragma unroll
        for (int nt = 0; nt < 4; ++nt) {
            int col2 = (wn * 64 + nt * 16 + lm) * 2;
#pragma unroll
            for (int r = 0; r < 4; ++r) {
                int row = yr0 + r;
                *(unsigned short*)(Ysb + row * 256 + (col2 ^ ((row & 15) << 4)))
                    = f2bf(acc[nt][r]);
            }
        }
    }

    // ---------------- phase B: out = x - Y @ W^T + b ----------------
#pragma unroll 1
    for (int ct = 0; ct < 8; ++ct) {
        __syncthreads();                 // ct=0: Ys visible; ct>0: prev Ws reads done
        GLW(ct);                         // async W tile -> LDS
        __syncthreads();                 // tile ready

        f32x4 oacc[4];
#pragma unroll
        for (int n = 0; n < 4; ++n) oacc[n] = (f32x4){0.f, 0.f, 0.f, 0.f};
#pragma unroll
        for (int kk = 0; kk < 128; kk += 32) {
            s16x8 a = *(const s16x8*)(Ysb + arow + (((kk + q * 8) * 2) ^ ms));
#pragma unroll
            for (int nt = 0; nt < 4; ++nt) {
                s16x8 b = *(const s16x8*)(Wsb + (wn * 64 + nt * 16 + lm) * 256
                                              + (((kk + q * 8) * 2) ^ ms));
                oacc[nt] = __builtin_amdgcn_mfma_f32_16x16x32_bf16(a, b, oacc[nt], 0, 0, 0);
            }
        }

        int orow = r0 + wm * 16 + q * 4;
#pragma unroll
        for (int nt = 0; nt < 4; ++nt) {
            int col = ct * 128 + wn * 64 + nt * 16 + lm;
            float bv = bias[col];
#pragma unroll
            for (int r = 0; r < 4; ++r) {
                size_t idx = (size_t)(orow + r) * DIM + col;
                out[idx] = x[idx] - oacc[nt][r] + bv;   // x re-read is L3-resident
            }
        }
    }
#undef LDX
#undef STX
#undef GLB
#undef GLW
}

// ---------------------------------------------------------------------------
extern "C" void kernel_launch(void* const* d_in, const int* in_sizes, int n_in,
                              void* d_out, int out_size, void* d_ws, size_t ws_size,
                              hipStream_t stream) {
    const float* x    = (const float*)d_in[0];
    const float* v    = (const float*)d_in[1];
    const float* bias = (const float*)d_in[2];
    float* out = (float*)d_out;

    char* ws = (char*)d_ws;
    float*          VnT   = (float*)(ws);                    // 512 KB  [NVEC][DIM] fp32
    unsigned short* VnT16 = (unsigned short*)(ws + 524288);  // 256 KB  [NVEC][DIM] bf16
    float*          G0    = (float*)(ws + 786432);           // 64 KB   raw Gram
    float*          T     = (float*)(ws + 851968);           // 64 KB
    float*          rn    = (float*)(ws + 917504);           // 512 B   col inv-norms
    unsigned short* W16   = (unsigned short*)(ws + 921600);  // 256 KB  [DIM][NVEC] bf16

    k_normgram<<<NVEC, 256, 0, stream>>>(v, VnT, VnT16, rn, G0);
    k_tinv<<<1, 256, 0, stream>>>(G0, rn, T);
    k_wmat<<<DIM / 8, 256, 0, stream>>>(VnT, T, W16);
    k_fused<<<BROWS / 64, 512, 0, stream>>>(x, VnT16, W16, bias, out);
}